// Round 1
// baseline (189.434 us; speedup 1.0000x reference)
//
#include <hip/hip_runtime.h>

#define HIDDEN 64
#define TSTEPS 1024
#define NROWS  8192
#define KEPS   1e-6f

// ---------------- Kernel A: per-row MLP -> params {l,g,s,prior} ----------------
__global__ __launch_bounds__(64) void bkt_mlp_kernel(
    const int* __restrict__ X, const float* __restrict__ embed,
    const float* __restrict__ W0, const float* __restrict__ b0,
    const float* __restrict__ W1, const float* __restrict__ b1,
    const float* __restrict__ Wout, const float* __restrict__ bout,
    float4* __restrict__ params)
{
    const int row = blockIdx.x;
    const int j   = threadIdx.x;   // 0..63, one hidden unit per lane
    __shared__ float sh[HIDDEN];

    const int skill = X[row];                       // wave-uniform scalar load
    sh[j] = embed[skill * HIDDEN + j];              // coalesced 256B
    __syncthreads();

    float acc = b0[j];
    #pragma unroll
    for (int k = 0; k < HIDDEN; ++k)
        acc = fmaf(sh[k], W0[k * HIDDEN + j], acc); // W0 coalesced across lanes
    float h0 = fmaxf(acc, 0.0f);
    __syncthreads();
    sh[j] = h0;
    __syncthreads();

    acc = b1[j];
    #pragma unroll
    for (int k = 0; k < HIDDEN; ++k)
        acc = fmaf(sh[k], W1[k * HIDDEN + j], acc);
    float h1 = fmaxf(acc, 0.0f);

    // head: out[c] = sum_k h1[k] * Wout[k*4+c]; lane k holds h1[k]
    float p0 = h1 * Wout[j * 4 + 0];
    float p1 = h1 * Wout[j * 4 + 1];
    float p2 = h1 * Wout[j * 4 + 2];
    float p3 = h1 * Wout[j * 4 + 3];
    #pragma unroll
    for (int off = 32; off >= 1; off >>= 1) {
        p0 += __shfl_down(p0, off, 64);
        p1 += __shfl_down(p1, off, 64);
        p2 += __shfl_down(p2, off, 64);
        p3 += __shfl_down(p3, off, 64);
    }
    if (j == 0) {
        float v0 = p0 + bout[0], v1 = p1 + bout[1], v2 = p2 + bout[2], v3 = p3 + bout[3];
        float4 r;
        r.x = fminf(fmaxf(1.0f / (1.0f + __expf(-v0)), KEPS), 1.0f - KEPS);
        r.y = fminf(fmaxf(1.0f / (1.0f + __expf(-v1)), KEPS), 1.0f - KEPS);
        r.z = fminf(fmaxf(1.0f / (1.0f + __expf(-v2)), KEPS), 1.0f - KEPS);
        r.w = fminf(fmaxf(1.0f / (1.0f + __expf(-v3)), KEPS), 1.0f - KEPS);
        params[row] = r;
    }
}

// ---------------- Kernel B: sequential BKT scan, LDS-tiled coalesced I/O ----------------
__global__ __launch_bounds__(64) void bkt_scan_kernel(
    const int* __restrict__ y, const float4* __restrict__ params,
    float* __restrict__ out_corr, float* __restrict__ out_lat)
{
    const int lane = threadIdx.x;        // row within this block's 64-row group
    const int base = blockIdx.x * 64;

    __shared__ int   sy  [64][65];       // +1 pad: (lane+tt)%32 -> 2-way aliasing (free)
    __shared__ float scor[64][65];
    __shared__ float slat[64][65];

    const float4 p = params[base + lane];
    const float l = p.x, g = p.y, s = p.z;
    float L = p.w;                        // latent = prior

    const float a   = 1.0f - s;           // (1-s)
    const float c1  = a - g;              // correct = L*c1 + g
    const float omg = 1.0f - g;
    const float c2  = s - omg;            // den0 = L*c2 + (1-g)
    const float oml = 1.0f - l;

    for (int tile = 0; tile < TSTEPS / 64; ++tile) {
        const int t0 = tile * 64;
        // stage y tile coalesced: lane covers t, loop covers rows
        for (int r = 0; r < 64; ++r)
            sy[r][lane] = y[(base + r) * TSTEPS + t0 + lane];
        __syncthreads();

        #pragma unroll
        for (int tt = 0; tt < 64; ++tt) {
            const int   yv      = sy[lane][tt];
            const float correct = fmaf(L, c1, g);
            const float den0    = fmaf(L, c2, omg);
            const float k1 = (L * a) * __builtin_amdgcn_rcpf(correct);
            const float k0 = (L * s) * __builtin_amdgcn_rcpf(den0);
            const float k  = (yv > 0) ? k1 : k0;   // true_correct>0.5 <=> y==1
            scor[lane][tt] = correct;
            slat[lane][tt] = L;
            L = fminf(fmaxf(fmaf(k, oml, l), KEPS), 1.0f - KEPS);
        }
        __syncthreads();

        // coalesced write-out of the 64x64 tiles
        for (int r = 0; r < 64; ++r) {
            const int o = (base + r) * TSTEPS + t0 + lane;
            out_corr[o] = scor[r][lane];
            out_lat [o] = slat[r][lane];
        }
        // no trailing barrier needed: next phase that touches scor/slat/sy is
        // separated by the post-staging __syncthreads above
    }
}

extern "C" void kernel_launch(void* const* d_in, const int* in_sizes, int n_in,
                              void* d_out, int out_size, void* d_ws, size_t ws_size,
                              hipStream_t stream) {
    const int*   X     = (const int*)  d_in[0];
    const int*   y     = (const int*)  d_in[1];
    const float* embed = (const float*)d_in[2];
    const float* W0    = (const float*)d_in[3];
    const float* b0    = (const float*)d_in[4];
    const float* W1    = (const float*)d_in[5];
    const float* b1    = (const float*)d_in[6];
    const float* Wout  = (const float*)d_in[7];
    const float* bout  = (const float*)d_in[8];

    float* out_corr = (float*)d_out;                       // output 0: corrects (B,T)
    float* out_lat  = out_corr + (size_t)NROWS * TSTEPS;   // output 1: latents  (B,T)
    float4* params  = (float4*)d_ws;                       // 8192 * 16B scratch

    bkt_mlp_kernel<<<NROWS, 64, 0, stream>>>(X, embed, W0, b0, W1, b1, Wout, bout, params);
    bkt_scan_kernel<<<NROWS / 64, 64, 0, stream>>>(y, params, out_corr, out_lat);
}

// Round 2
// 141.668 us; speedup vs baseline: 1.3372x; 1.3372x over previous
//
#include <hip/hip_runtime.h>

#define HIDDEN 64
#define TSTEPS 1024
#define NROWS  8192
#define NCHUNK 16
#define CLEN   64
#define KEPS   1e-6f

// ---------------- Kernel A: per-row MLP -> params {l,g,s,prior} ----------------
__global__ __launch_bounds__(64) void bkt_mlp_kernel(
    const int* __restrict__ X, const float* __restrict__ embed,
    const float* __restrict__ W0, const float* __restrict__ b0,
    const float* __restrict__ W1, const float* __restrict__ b1,
    const float* __restrict__ Wout, const float* __restrict__ bout,
    float4* __restrict__ params)
{
    const int row = blockIdx.x;
    const int j   = threadIdx.x;
    __shared__ float sh[HIDDEN];

    const int skill = X[row];
    sh[j] = embed[skill * HIDDEN + j];
    __syncthreads();

    float acc = b0[j];
    #pragma unroll
    for (int k = 0; k < HIDDEN; ++k)
        acc = fmaf(sh[k], W0[k * HIDDEN + j], acc);
    float h0 = fmaxf(acc, 0.0f);
    __syncthreads();
    sh[j] = h0;
    __syncthreads();

    acc = b1[j];
    #pragma unroll
    for (int k = 0; k < HIDDEN; ++k)
        acc = fmaf(sh[k], W1[k * HIDDEN + j], acc);
    float h1 = fmaxf(acc, 0.0f);

    float p0 = h1 * Wout[j * 4 + 0];
    float p1 = h1 * Wout[j * 4 + 1];
    float p2 = h1 * Wout[j * 4 + 2];
    float p3 = h1 * Wout[j * 4 + 3];
    #pragma unroll
    for (int off = 32; off >= 1; off >>= 1) {
        p0 += __shfl_down(p0, off, 64);
        p1 += __shfl_down(p1, off, 64);
        p2 += __shfl_down(p2, off, 64);
        p3 += __shfl_down(p3, off, 64);
    }
    if (j == 0) {
        float v0 = p0 + bout[0], v1 = p1 + bout[1], v2 = p2 + bout[2], v3 = p3 + bout[3];
        float4 r;
        r.x = fminf(fmaxf(1.0f / (1.0f + __expf(-v0)), KEPS), 1.0f - KEPS);
        r.y = fminf(fmaxf(1.0f / (1.0f + __expf(-v1)), KEPS), 1.0f - KEPS);
        r.z = fminf(fmaxf(1.0f / (1.0f + __expf(-v2)), KEPS), 1.0f - KEPS);
        r.w = fminf(fmaxf(1.0f / (1.0f + __expf(-v3)), KEPS), 1.0f - KEPS);
        params[row] = r;
    }
}

// ---------------- P1: per (row,chunk) Mobius matrix + y bitmask ----------------
// Step as Mobius transform of latent L: L' = (m00*L+m01)/(m10*L+m11).
//   y=1: k1 = L*a1/(L*c1+d1), a1=1-s, c1=1-s-g, d1=g
//   y=0: k0 = L*a0/(L*c0+d0), a0=s,   c0=s+g-1, d0=1-g
//   L' = l + (1-l)*k  =>  E = [[l*c + (1-l)*a, l*d], [c, d]]
__global__ __launch_bounds__(64) void bkt_chunk_mats(
    const int* __restrict__ y, const float4* __restrict__ params,
    float4* __restrict__ Mbuf, unsigned long long* __restrict__ maskbuf)
{
    const int lane = threadIdx.x;
    const int base = blockIdx.x * 64;
    const int c    = blockIdx.y;
    const int t0   = c * CLEN;

    // coalesced y read; compress row r's 64 steps into a 64-bit mask via ballot
    unsigned long long mask = 0ull;
    #pragma unroll 8
    for (int r = 0; r < 64; ++r) {
        int val = y[(size_t)(base + r) * TSTEPS + t0 + lane];
        unsigned long long bal = __ballot(val > 0);
        if (lane == r) mask = bal;
    }

    const float4 p = params[base + lane];
    const float l = p.x, g = p.y, s = p.z;
    const float c1 = 1.f - s - g, d1 = g;
    const float e00_1 = fmaf(l, c1, (1.f - l) * (1.f - s));
    const float e01_1 = l * d1;
    const float c0 = s + g - 1.f, d0 = 1.f - g;
    const float e00_0 = fmaf(l, c0, (1.f - l) * s);
    const float e01_0 = l * d0;

    float m00 = 1.f, m01 = 0.f, m10 = 0.f, m11 = 1.f;
    #pragma unroll
    for (int tt = 0; tt < CLEN; ++tt) {
        const bool one = (mask >> tt) & 1ull;
        const float e00 = one ? e00_1 : e00_0;
        const float e01 = one ? e01_1 : e01_0;
        const float e10 = one ? c1 : c0;
        const float e11 = one ? d1 : d0;
        float n00 = fmaf(e00, m00, e01 * m10);
        float n01 = fmaf(e00, m01, e01 * m11);
        float n10 = fmaf(e10, m00, e11 * m10);
        float n11 = fmaf(e10, m01, e11 * m11);
        if ((tt & 3) == 3) {   // renormalize: m11 > 0 always (positive denominators)
            float inv = __builtin_amdgcn_rcpf(n11);
            m00 = n00 * inv; m01 = n01 * inv; m10 = n10 * inv; m11 = 1.f;
        } else {
            m00 = n00; m01 = n01; m10 = n10; m11 = n11;
        }
    }
    Mbuf  [(size_t)c * NROWS + base + lane] = make_float4(m00, m01, m10, m11);
    maskbuf[(size_t)c * NROWS + base + lane] = mask;
}

// ---------------- P2: per-row sequential compose over 16 chunks -> start latents ----
__global__ __launch_bounds__(256) void bkt_chunk_starts(
    const float4* __restrict__ params, const float4* __restrict__ Mbuf,
    float* __restrict__ L0buf)
{
    const int r = blockIdx.x * 256 + threadIdx.x;
    float L = params[r].w;   // prior
    #pragma unroll
    for (int c = 0; c < NCHUNK; ++c) {
        L0buf[(size_t)c * NROWS + r] = L;
        float4 M = Mbuf[(size_t)c * NROWS + r];
        float num = fmaf(M.x, L, M.y);
        float den = fmaf(M.z, L, M.w);
        L = num * __builtin_amdgcn_rcpf(den);
        L = fminf(fmaxf(L, KEPS), 1.f - KEPS);
    }
}

// ---------------- P3: exact clipped recurrence per (row,chunk), tiled output ----
__global__ __launch_bounds__(64) void bkt_chunk_scan(
    const float4* __restrict__ params, const unsigned long long* __restrict__ maskbuf,
    const float* __restrict__ L0buf,
    float* __restrict__ out_corr, float* __restrict__ out_lat)
{
    const int lane = threadIdx.x;
    const int base = blockIdx.x * 64;
    const int c    = blockIdx.y;
    const int row  = base + lane;

    __shared__ float scor[64][17];
    __shared__ float slat[64][17];

    const float4 p = params[row];
    const float l = p.x, g = p.y, s = p.z;
    const float a   = 1.f - s;
    const float c1v = a - g;
    const float omg = 1.f - g;
    const float c2v = s - omg;
    const float oml = 1.f - l;

    const unsigned long long mask = maskbuf[(size_t)c * NROWS + row];
    float L = L0buf[(size_t)c * NROWS + row];

    const int subr = lane >> 4;   // 0..3
    const int tq   = lane & 15;   // 0..15

    for (int gq = 0; gq < 4; ++gq) {
        #pragma unroll
        for (int q = 0; q < 16; ++q) {
            const int tt = gq * 16 + q;
            const float correct = fmaf(L, c1v, g);
            const float den0    = fmaf(L, c2v, omg);
            const float k1 = (L * a) * __builtin_amdgcn_rcpf(correct);
            const float k0 = (L * s) * __builtin_amdgcn_rcpf(den0);
            const bool one = (mask >> tt) & 1ull;
            const float k = one ? k1 : k0;
            scor[lane][q] = correct;
            slat[lane][q] = L;
            L = fminf(fmaxf(fmaf(k, oml, l), KEPS), 1.f - KEPS);
        }
        __syncthreads();
        #pragma unroll
        for (int it = 0; it < 16; ++it) {
            const int rr = it * 4 + subr;
            const size_t o = (size_t)(base + rr) * TSTEPS + c * CLEN + gq * 16 + tq;
            out_corr[o] = scor[rr][tq];
            out_lat [o] = slat[rr][tq];
        }
        __syncthreads();
    }
}

extern "C" void kernel_launch(void* const* d_in, const int* in_sizes, int n_in,
                              void* d_out, int out_size, void* d_ws, size_t ws_size,
                              hipStream_t stream) {
    const int*   X     = (const int*)  d_in[0];
    const int*   y     = (const int*)  d_in[1];
    const float* embed = (const float*)d_in[2];
    const float* W0    = (const float*)d_in[3];
    const float* b0    = (const float*)d_in[4];
    const float* W1    = (const float*)d_in[5];
    const float* b1    = (const float*)d_in[6];
    const float* Wout  = (const float*)d_in[7];
    const float* bout  = (const float*)d_in[8];

    float* out_corr = (float*)d_out;
    float* out_lat  = out_corr + (size_t)NROWS * TSTEPS;

    // workspace layout
    char* ws = (char*)d_ws;
    float4*             paramsb = (float4*)(ws);                        // 128 KB
    float4*             Mbuf    = (float4*)(ws + (128 << 10));          // 2 MB
    unsigned long long* maskbuf = (unsigned long long*)(ws + (128 << 10) + (2 << 20)); // 1 MB
    float*              L0buf   = (float*)(ws + (128 << 10) + (3 << 20));              // 512 KB

    bkt_mlp_kernel<<<NROWS, 64, 0, stream>>>(X, embed, W0, b0, W1, b1, Wout, bout, paramsb);
    bkt_chunk_mats<<<dim3(NROWS / 64, NCHUNK), 64, 0, stream>>>(y, paramsb, Mbuf, maskbuf);
    bkt_chunk_starts<<<NROWS / 256, 256, 0, stream>>>(paramsb, Mbuf, L0buf);
    bkt_chunk_scan<<<dim3(NROWS / 64, NCHUNK), 64, 0, stream>>>(paramsb, maskbuf, L0buf, out_corr, out_lat);
}

// Round 3
// 136.259 us; speedup vs baseline: 1.3902x; 1.0397x over previous
//
#include <hip/hip_runtime.h>

#define TSTEPS 1024
#define NROWS  8192
#define NCHUNK 16
#define CLEN   64
#define KEPS   1e-6f

// One wave = 4 rows. Phases:
//  A) MLP: lane j = hidden unit j; 4 rows' embeds in LDS, broadcast via ds_read_b128.
//  B) masks: 64 ballots -> per-(row,chunk) 64-bit y-mask, latched to lane rs*16+c.
//  C) P1: every lane composes its (row,chunk) 64-step Mobius matrix (renorm /4).
//  D) P2: per row-group of 16 lanes, 16-step shuffle chain -> chunk-start latents.
//  E) P3: exact clipped recurrence per (row,chunk); float4 windowed stores.
__global__ __launch_bounds__(64) void bkt_fused(
    const int* __restrict__ X, const int* __restrict__ y,
    const float* __restrict__ embed,
    const float* __restrict__ W0, const float* __restrict__ b0,
    const float* __restrict__ W1, const float* __restrict__ b1,
    const float* __restrict__ Wout, const float* __restrict__ bout,
    float* __restrict__ out_corr, float* __restrict__ out_lat)
{
    const int lane    = threadIdx.x;
    const int rowbase = blockIdx.x * 4;

    __shared__ float sh[4][64];

    // ---- Phase A: MLP ----
    #pragma unroll
    for (int rs = 0; rs < 4; ++rs) {
        const int skill = X[rowbase + rs];
        sh[rs][lane] = embed[(size_t)skill * 64 + lane];
    }
    __syncthreads();

    float a0 = b0[lane], a1 = a0, a2 = a0, a3 = a0;
    #pragma unroll
    for (int k4 = 0; k4 < 16; ++k4) {
        const float4 e0 = *(const float4*)&sh[0][k4 * 4];
        const float4 e1 = *(const float4*)&sh[1][k4 * 4];
        const float4 e2 = *(const float4*)&sh[2][k4 * 4];
        const float4 e3 = *(const float4*)&sh[3][k4 * 4];
        const float w0 = W0[(k4 * 4 + 0) * 64 + lane];
        const float w1 = W0[(k4 * 4 + 1) * 64 + lane];
        const float w2 = W0[(k4 * 4 + 2) * 64 + lane];
        const float w3 = W0[(k4 * 4 + 3) * 64 + lane];
        a0 = fmaf(e0.x, w0, a0); a0 = fmaf(e0.y, w1, a0); a0 = fmaf(e0.z, w2, a0); a0 = fmaf(e0.w, w3, a0);
        a1 = fmaf(e1.x, w0, a1); a1 = fmaf(e1.y, w1, a1); a1 = fmaf(e1.z, w2, a1); a1 = fmaf(e1.w, w3, a1);
        a2 = fmaf(e2.x, w0, a2); a2 = fmaf(e2.y, w1, a2); a2 = fmaf(e2.z, w2, a2); a2 = fmaf(e2.w, w3, a2);
        a3 = fmaf(e3.x, w0, a3); a3 = fmaf(e3.y, w1, a3); a3 = fmaf(e3.z, w2, a3); a3 = fmaf(e3.w, w3, a3);
    }
    __syncthreads();
    sh[0][lane] = fmaxf(a0, 0.f);
    sh[1][lane] = fmaxf(a1, 0.f);
    sh[2][lane] = fmaxf(a2, 0.f);
    sh[3][lane] = fmaxf(a3, 0.f);
    __syncthreads();

    a0 = b1[lane]; a1 = a0; a2 = a0; a3 = a0;
    #pragma unroll
    for (int k4 = 0; k4 < 16; ++k4) {
        const float4 e0 = *(const float4*)&sh[0][k4 * 4];
        const float4 e1 = *(const float4*)&sh[1][k4 * 4];
        const float4 e2 = *(const float4*)&sh[2][k4 * 4];
        const float4 e3 = *(const float4*)&sh[3][k4 * 4];
        const float w0 = W1[(k4 * 4 + 0) * 64 + lane];
        const float w1 = W1[(k4 * 4 + 1) * 64 + lane];
        const float w2 = W1[(k4 * 4 + 2) * 64 + lane];
        const float w3 = W1[(k4 * 4 + 3) * 64 + lane];
        a0 = fmaf(e0.x, w0, a0); a0 = fmaf(e0.y, w1, a0); a0 = fmaf(e0.z, w2, a0); a0 = fmaf(e0.w, w3, a0);
        a1 = fmaf(e1.x, w0, a1); a1 = fmaf(e1.y, w1, a1); a1 = fmaf(e1.z, w2, a1); a1 = fmaf(e1.w, w3, a1);
        a2 = fmaf(e2.x, w0, a2); a2 = fmaf(e2.y, w1, a2); a2 = fmaf(e2.z, w2, a2); a2 = fmaf(e2.w, w3, a2);
        a3 = fmaf(e3.x, w0, a3); a3 = fmaf(e3.y, w1, a3); a3 = fmaf(e3.z, w2, a3); a3 = fmaf(e3.w, w3, a3);
    }
    const float h0r = fmaxf(a0, 0.f), h1r = fmaxf(a1, 0.f);
    const float h2r = fmaxf(a2, 0.f), h3r = fmaxf(a3, 0.f);

    // head: p[rs][c] = sum_j h_rs[j]*Wout[j*4+c]
    const float4 wo = ((const float4*)Wout)[lane];
    float p[4][4];
    p[0][0] = h0r * wo.x; p[0][1] = h0r * wo.y; p[0][2] = h0r * wo.z; p[0][3] = h0r * wo.w;
    p[1][0] = h1r * wo.x; p[1][1] = h1r * wo.y; p[1][2] = h1r * wo.z; p[1][3] = h1r * wo.w;
    p[2][0] = h2r * wo.x; p[2][1] = h2r * wo.y; p[2][2] = h2r * wo.z; p[2][3] = h2r * wo.w;
    p[3][0] = h3r * wo.x; p[3][1] = h3r * wo.y; p[3][2] = h3r * wo.z; p[3][3] = h3r * wo.w;
    #pragma unroll
    for (int off = 32; off >= 1; off >>= 1) {
        #pragma unroll
        for (int rs = 0; rs < 4; ++rs)
            #pragma unroll
            for (int c = 0; c < 4; ++c)
                p[rs][c] += __shfl_xor(p[rs][c], off, 64);
    }
    const float4 bo = *(const float4*)bout;

    const int rsme = lane >> 4;      // my row within the 4-row group
    const int cme  = lane & 15;      // my chunk
    float v0 = (rsme == 0) ? p[0][0] : (rsme == 1) ? p[1][0] : (rsme == 2) ? p[2][0] : p[3][0];
    float v1 = (rsme == 0) ? p[0][1] : (rsme == 1) ? p[1][1] : (rsme == 2) ? p[2][1] : p[3][1];
    float v2 = (rsme == 0) ? p[0][2] : (rsme == 1) ? p[1][2] : (rsme == 2) ? p[2][2] : p[3][2];
    float v3 = (rsme == 0) ? p[0][3] : (rsme == 1) ? p[1][3] : (rsme == 2) ? p[2][3] : p[3][3];
    v0 += bo.x; v1 += bo.y; v2 += bo.z; v3 += bo.w;

    const float l     = fminf(fmaxf(1.0f / (1.0f + __expf(-v0)), KEPS), 1.0f - KEPS);
    const float g     = fminf(fmaxf(1.0f / (1.0f + __expf(-v1)), KEPS), 1.0f - KEPS);
    const float s     = fminf(fmaxf(1.0f / (1.0f + __expf(-v2)), KEPS), 1.0f - KEPS);
    const float prior = fminf(fmaxf(1.0f / (1.0f + __expf(-v3)), KEPS), 1.0f - KEPS);

    // ---- Phase B: y-masks via ballot; latch to lane rs*16+c ----
    unsigned long long mask = 0ull;
    #pragma unroll
    for (int rs = 0; rs < 4; ++rs) {
        #pragma unroll
        for (int c = 0; c < 16; ++c) {
            const int val = y[(size_t)(rowbase + rs) * TSTEPS + c * CLEN + lane];
            const unsigned long long bal = __ballot(val > 0);
            if (lane == rs * 16 + c) mask = bal;
        }
    }

    // ---- Phase C: compose 64-step Mobius matrix for (my row, my chunk) ----
    const float c1 = 1.f - s - g, d1 = g;
    const float e00_1 = fmaf(l, c1, (1.f - l) * (1.f - s));
    const float e01_1 = l * d1;
    const float c0 = s + g - 1.f, d0 = 1.f - g;
    const float e00_0 = fmaf(l, c0, (1.f - l) * s);
    const float e01_0 = l * d0;

    float m00 = 1.f, m01 = 0.f, m10 = 0.f, m11 = 1.f;
    #pragma unroll
    for (int tt = 0; tt < CLEN; ++tt) {
        const bool one = (mask >> tt) & 1ull;
        const float e00 = one ? e00_1 : e00_0;
        const float e01 = one ? e01_1 : e01_0;
        const float e10 = one ? c1 : c0;
        const float e11 = one ? d1 : d0;
        float n00 = fmaf(e00, m00, e01 * m10);
        float n01 = fmaf(e00, m01, e01 * m11);
        float n10 = fmaf(e10, m00, e11 * m10);
        float n11 = fmaf(e10, m01, e11 * m11);
        if ((tt & 3) == 3) {   // renormalize: m11 > 0 (positive denominators)
            const float inv = __builtin_amdgcn_rcpf(n11);
            m00 = n00 * inv; m01 = n01 * inv; m10 = n10 * inv; m11 = 1.f;
        } else {
            m00 = n00; m01 = n01; m10 = n10; m11 = n11;
        }
    }

    // ---- Phase D: per-row serial compose over 16 chunks -> my chunk's start latent ----
    const int grp = lane & 48;
    float L  = prior;
    float L0 = prior;
    #pragma unroll
    for (int cc = 0; cc < 16; ++cc) {
        const float q00 = __shfl(m00, grp | cc, 64);
        const float q01 = __shfl(m01, grp | cc, 64);
        const float q10 = __shfl(m10, grp | cc, 64);
        const float q11 = __shfl(m11, grp | cc, 64);
        if (cme == cc) L0 = L;
        const float num = fmaf(q00, L, q01);
        const float den = fmaf(q10, L, q11);
        L = num * __builtin_amdgcn_rcpf(den);
        L = fminf(fmaxf(L, KEPS), 1.f - KEPS);
    }

    // ---- Phase E: exact clipped recurrence; float4 windowed stores ----
    const float a    = 1.f - s;
    const float c1v  = a - g;
    const float omg  = 1.f - g;
    const float c2v  = s - omg;
    const float oml  = 1.f - l;

    const size_t obase = (size_t)(rowbase + rsme) * TSTEPS + cme * CLEN;
    float Lc = L0;
    #pragma unroll
    for (int w = 0; w < 4; ++w) {
        float cr[4], lt[4];
        #pragma unroll
        for (int q = 0; q < 16; ++q) {
            const int tt = w * 16 + q;
            const float correct = fmaf(Lc, c1v, g);
            const float den0    = fmaf(Lc, c2v, omg);
            const float k1 = (Lc * a) * __builtin_amdgcn_rcpf(correct);
            const float k0 = (Lc * s) * __builtin_amdgcn_rcpf(den0);
            const bool one = (mask >> tt) & 1ull;
            const float k = one ? k1 : k0;
            cr[q & 3] = correct;
            lt[q & 3] = Lc;
            Lc = fminf(fmaxf(fmaf(k, oml, l), KEPS), 1.f - KEPS);
            if ((q & 3) == 3) {
                const size_t o = obase + w * 16 + (q - 3);
                *(float4*)&out_corr[o] = make_float4(cr[0], cr[1], cr[2], cr[3]);
                *(float4*)&out_lat [o] = make_float4(lt[0], lt[1], lt[2], lt[3]);
            }
        }
    }
}

extern "C" void kernel_launch(void* const* d_in, const int* in_sizes, int n_in,
                              void* d_out, int out_size, void* d_ws, size_t ws_size,
                              hipStream_t stream) {
    const int*   X     = (const int*)  d_in[0];
    const int*   y     = (const int*)  d_in[1];
    const float* embed = (const float*)d_in[2];
    const float* W0    = (const float*)d_in[3];
    const float* b0    = (const float*)d_in[4];
    const float* W1    = (const float*)d_in[5];
    const float* b1    = (const float*)d_in[6];
    const float* Wout  = (const float*)d_in[7];
    const float* bout  = (const float*)d_in[8];

    float* out_corr = (float*)d_out;
    float* out_lat  = out_corr + (size_t)NROWS * TSTEPS;

    bkt_fused<<<NROWS / 4, 64, 0, stream>>>(X, y, embed, W0, b0, W1, b1, Wout, bout,
                                            out_corr, out_lat);
}

// Round 4
// 132.650 us; speedup vs baseline: 1.4281x; 1.0272x over previous
//
#include <hip/hip_runtime.h>

#define TSTEPS 1024
#define NROWS  8192
#define CLEN   16      // steps per chunk = steps per lane
#define KEPS   1e-6f

__device__ __forceinline__ float clampP(float x) {
    return fminf(fmaxf(x, KEPS), 1.f - KEPS);
}
__device__ __forceinline__ float sigm(float v) {
    return 1.0f / (1.0f + __expf(-v));
}

// ---------------- K1: per-row MLP -> params {l,g,s,prior}; 4 rows/wave, 16 rows/block ----
__global__ __launch_bounds__(256) void bkt_params_v4(
    const int* __restrict__ X, const float* __restrict__ embed,
    const float* __restrict__ W0, const float* __restrict__ b0,
    const float* __restrict__ W1, const float* __restrict__ b1,
    const float* __restrict__ Wout, const float* __restrict__ bout,
    float4* __restrict__ params)
{
    const int lane    = threadIdx.x & 63;
    const int wid     = threadIdx.x >> 6;
    const int rowbase = blockIdx.x * 16 + wid * 4;

    __shared__ float sh[4][4][64];
    float (*shw)[64] = sh[wid];

    #pragma unroll
    for (int rs = 0; rs < 4; ++rs) {
        const int skill = X[rowbase + rs];
        shw[rs][lane] = embed[(size_t)skill * 64 + lane];
    }
    __syncthreads();

    float a0 = b0[lane], a1 = a0, a2 = a0, a3 = a0;
    #pragma unroll
    for (int k4 = 0; k4 < 16; ++k4) {
        const float4 e0 = *(const float4*)&shw[0][k4 * 4];
        const float4 e1 = *(const float4*)&shw[1][k4 * 4];
        const float4 e2 = *(const float4*)&shw[2][k4 * 4];
        const float4 e3 = *(const float4*)&shw[3][k4 * 4];
        const float w0 = W0[(k4 * 4 + 0) * 64 + lane];
        const float w1 = W0[(k4 * 4 + 1) * 64 + lane];
        const float w2 = W0[(k4 * 4 + 2) * 64 + lane];
        const float w3 = W0[(k4 * 4 + 3) * 64 + lane];
        a0 = fmaf(e0.x, w0, a0); a0 = fmaf(e0.y, w1, a0); a0 = fmaf(e0.z, w2, a0); a0 = fmaf(e0.w, w3, a0);
        a1 = fmaf(e1.x, w0, a1); a1 = fmaf(e1.y, w1, a1); a1 = fmaf(e1.z, w2, a1); a1 = fmaf(e1.w, w3, a1);
        a2 = fmaf(e2.x, w0, a2); a2 = fmaf(e2.y, w1, a2); a2 = fmaf(e2.z, w2, a2); a2 = fmaf(e2.w, w3, a2);
        a3 = fmaf(e3.x, w0, a3); a3 = fmaf(e3.y, w1, a3); a3 = fmaf(e3.z, w2, a3); a3 = fmaf(e3.w, w3, a3);
    }
    __syncthreads();
    shw[0][lane] = fmaxf(a0, 0.f);
    shw[1][lane] = fmaxf(a1, 0.f);
    shw[2][lane] = fmaxf(a2, 0.f);
    shw[3][lane] = fmaxf(a3, 0.f);
    __syncthreads();

    a0 = b1[lane]; a1 = a0; a2 = a0; a3 = a0;
    #pragma unroll
    for (int k4 = 0; k4 < 16; ++k4) {
        const float4 e0 = *(const float4*)&shw[0][k4 * 4];
        const float4 e1 = *(const float4*)&shw[1][k4 * 4];
        const float4 e2 = *(const float4*)&shw[2][k4 * 4];
        const float4 e3 = *(const float4*)&shw[3][k4 * 4];
        const float w0 = W1[(k4 * 4 + 0) * 64 + lane];
        const float w1 = W1[(k4 * 4 + 1) * 64 + lane];
        const float w2 = W1[(k4 * 4 + 2) * 64 + lane];
        const float w3 = W1[(k4 * 4 + 3) * 64 + lane];
        a0 = fmaf(e0.x, w0, a0); a0 = fmaf(e0.y, w1, a0); a0 = fmaf(e0.z, w2, a0); a0 = fmaf(e0.w, w3, a0);
        a1 = fmaf(e1.x, w0, a1); a1 = fmaf(e1.y, w1, a1); a1 = fmaf(e1.z, w2, a1); a1 = fmaf(e1.w, w3, a1);
        a2 = fmaf(e2.x, w0, a2); a2 = fmaf(e2.y, w1, a2); a2 = fmaf(e2.z, w2, a2); a2 = fmaf(e2.w, w3, a2);
        a3 = fmaf(e3.x, w0, a3); a3 = fmaf(e3.y, w1, a3); a3 = fmaf(e3.z, w2, a3); a3 = fmaf(e3.w, w3, a3);
    }
    const float h0r = fmaxf(a0, 0.f), h1r = fmaxf(a1, 0.f);
    const float h2r = fmaxf(a2, 0.f), h3r = fmaxf(a3, 0.f);

    const float4 wo = ((const float4*)Wout)[lane];
    float p[4][4];
    p[0][0] = h0r * wo.x; p[0][1] = h0r * wo.y; p[0][2] = h0r * wo.z; p[0][3] = h0r * wo.w;
    p[1][0] = h1r * wo.x; p[1][1] = h1r * wo.y; p[1][2] = h1r * wo.z; p[1][3] = h1r * wo.w;
    p[2][0] = h2r * wo.x; p[2][1] = h2r * wo.y; p[2][2] = h2r * wo.z; p[2][3] = h2r * wo.w;
    p[3][0] = h3r * wo.x; p[3][1] = h3r * wo.y; p[3][2] = h3r * wo.z; p[3][3] = h3r * wo.w;
    #pragma unroll
    for (int off = 32; off >= 1; off >>= 1) {
        #pragma unroll
        for (int rs = 0; rs < 4; ++rs)
            #pragma unroll
            for (int c = 0; c < 4; ++c)
                p[rs][c] += __shfl_xor(p[rs][c], off, 64);
    }
    const float4 bo = *(const float4*)bout;
    // lane rs in 0..3 writes row rowbase+rs (values are wave-uniform after reduction)
    float v0 = (lane == 0) ? p[0][0] : (lane == 1) ? p[1][0] : (lane == 2) ? p[2][0] : p[3][0];
    float v1 = (lane == 0) ? p[0][1] : (lane == 1) ? p[1][1] : (lane == 2) ? p[2][1] : p[3][1];
    float v2 = (lane == 0) ? p[0][2] : (lane == 1) ? p[1][2] : (lane == 2) ? p[2][2] : p[3][2];
    float v3 = (lane == 0) ? p[0][3] : (lane == 1) ? p[1][3] : (lane == 2) ? p[2][3] : p[3][3];
    if (lane < 4) {
        float4 r;
        r.x = clampP(sigm(v0 + bo.x));
        r.y = clampP(sigm(v1 + bo.y));
        r.z = clampP(sigm(v2 + bo.z));
        r.w = clampP(sigm(v3 + bo.w));
        params[rowbase + lane] = r;
    }
}

// ---------------- K2: one wave per row; lane = 16-step time chunk ----------------
__global__ __launch_bounds__(256) void bkt_scan_v4(
    const int* __restrict__ y, const float4* __restrict__ params,
    float* __restrict__ out_corr, float* __restrict__ out_lat)
{
    const int lane = threadIdx.x & 63;
    const int row  = blockIdx.x * 4 + (threadIdx.x >> 6);

    const float4 p = params[row];
    const float l = p.x, g = p.y, s = p.z, prior = p.w;

    // my chunk's 16 y values (64 B contiguous per lane, wave covers the whole row)
    const int4* yb = (const int4*)(y + (size_t)row * TSTEPS + lane * CLEN);
    const int4 v0 = yb[0], v1 = yb[1], v2 = yb[2], v3 = yb[3];
    unsigned msk = 0;
    msk |= (v0.x > 0) ? 1u << 0  : 0u; msk |= (v0.y > 0) ? 1u << 1  : 0u;
    msk |= (v0.z > 0) ? 1u << 2  : 0u; msk |= (v0.w > 0) ? 1u << 3  : 0u;
    msk |= (v1.x > 0) ? 1u << 4  : 0u; msk |= (v1.y > 0) ? 1u << 5  : 0u;
    msk |= (v1.z > 0) ? 1u << 6  : 0u; msk |= (v1.w > 0) ? 1u << 7  : 0u;
    msk |= (v2.x > 0) ? 1u << 8  : 0u; msk |= (v2.y > 0) ? 1u << 9  : 0u;
    msk |= (v2.z > 0) ? 1u << 10 : 0u; msk |= (v2.w > 0) ? 1u << 11 : 0u;
    msk |= (v3.x > 0) ? 1u << 12 : 0u; msk |= (v3.y > 0) ? 1u << 13 : 0u;
    msk |= (v3.z > 0) ? 1u << 14 : 0u; msk |= (v3.w > 0) ? 1u << 15 : 0u;

    // step as Mobius: L' = (m00*L+m01)/(m10*L+m11)
    const float c1 = 1.f - s - g, d1 = g;             // y=1 denominator coeffs
    const float e00_1 = fmaf(l, c1, (1.f - l) * (1.f - s));
    const float e01_1 = l * d1;
    const float c0 = s + g - 1.f, d0 = 1.f - g;       // y=0
    const float e00_0 = fmaf(l, c0, (1.f - l) * s);
    const float e01_0 = l * d0;

    // Phase C: compose my chunk's 16 step matrices (renorm every 4; m11 > 0)
    float m00 = 1.f, m01 = 0.f, m10 = 0.f, m11 = 1.f;
    #pragma unroll
    for (int t = 0; t < CLEN; ++t) {
        const bool one = (msk >> t) & 1u;
        const float e00 = one ? e00_1 : e00_0;
        const float e01 = one ? e01_1 : e01_0;
        const float e10 = one ? c1 : c0;
        const float e11 = one ? d1 : d0;
        const float n00 = fmaf(e00, m00, e01 * m10);
        const float n01 = fmaf(e00, m01, e01 * m11);
        const float n10 = fmaf(e10, m00, e11 * m10);
        const float n11 = fmaf(e10, m01, e11 * m11);
        if ((t & 3) == 3) {
            const float inv = __builtin_amdgcn_rcpf(n11);
            m00 = n00 * inv; m01 = n01 * inv; m10 = n10 * inv; m11 = 1.f;
        } else {
            m00 = n00; m01 = n01; m10 = n10; m11 = n11;
        }
    }

    // Phase D: inclusive Hillis-Steele prefix over the 64 chunk matrices
    float s00 = m00, s01 = m01, s10 = m10, s11 = m11;
    #pragma unroll
    for (int d = 1; d < 64; d <<= 1) {
        const float t00 = __shfl_up(s00, d, 64);
        const float t01 = __shfl_up(s01, d, 64);
        const float t10 = __shfl_up(s10, d, 64);
        const float t11 = __shfl_up(s11, d, 64);
        if (lane >= d) {
            const float r00 = fmaf(s00, t00, s01 * t10);
            const float r01 = fmaf(s00, t01, s01 * t11);
            const float r10 = fmaf(s10, t00, s11 * t10);
            const float r11 = fmaf(s10, t01, s11 * t11);
            const float inv = __builtin_amdgcn_rcpf(r11);
            s00 = r00 * inv; s01 = r01 * inv; s10 = r10 * inv; s11 = 1.f;
        }
    }
    // exclusive prefix -> my chunk-start latent
    const float x00 = __shfl_up(s00, 1, 64);
    const float x01 = __shfl_up(s01, 1, 64);
    const float x10 = __shfl_up(s10, 1, 64);
    const float x11 = __shfl_up(s11, 1, 64);
    float L0;
    if (lane == 0) {
        L0 = prior;
    } else {
        const float num = fmaf(x00, prior, x01);
        const float den = fmaf(x10, prior, x11);
        L0 = clampP(num * __builtin_amdgcn_rcpf(den));
    }

    // Phase E: exact clipped recurrence for my 16 steps; one 64B line per output
    const float a   = 1.f - s;
    const float omg = 1.f - g;
    const float oml = 1.f - l;
    float* oc = out_corr + (size_t)row * TSTEPS + lane * CLEN;
    float* ol = out_lat  + (size_t)row * TSTEPS + lane * CLEN;
    float Lc = L0;
    #pragma unroll
    for (int w = 0; w < 4; ++w) {
        float cr[4], lt[4];
        #pragma unroll
        for (int q = 0; q < 4; ++q) {
            const int t = w * 4 + q;
            const float correct = fmaf(Lc, c1, g);    // L*(1-s-g)+g
            const float den0    = fmaf(Lc, c0, omg);  // L*(s+g-1)+(1-g)
            const float k1 = (Lc * a) * __builtin_amdgcn_rcpf(correct);
            const float k0 = (Lc * s) * __builtin_amdgcn_rcpf(den0);
            const bool one = (msk >> t) & 1u;
            const float k = one ? k1 : k0;
            cr[q] = correct;
            lt[q] = Lc;
            Lc = clampP(fmaf(k, oml, l));
        }
        *(float4*)(oc + w * 4) = make_float4(cr[0], cr[1], cr[2], cr[3]);
        *(float4*)(ol + w * 4) = make_float4(lt[0], lt[1], lt[2], lt[3]);
    }
}

extern "C" void kernel_launch(void* const* d_in, const int* in_sizes, int n_in,
                              void* d_out, int out_size, void* d_ws, size_t ws_size,
                              hipStream_t stream) {
    const int*   X     = (const int*)  d_in[0];
    const int*   y     = (const int*)  d_in[1];
    const float* embed = (const float*)d_in[2];
    const float* W0    = (const float*)d_in[3];
    const float* b0    = (const float*)d_in[4];
    const float* W1    = (const float*)d_in[5];
    const float* b1    = (const float*)d_in[6];
    const float* Wout  = (const float*)d_in[7];
    const float* bout  = (const float*)d_in[8];

    float* out_corr = (float*)d_out;
    float* out_lat  = out_corr + (size_t)NROWS * TSTEPS;
    float4* paramsb = (float4*)d_ws;   // 128 KB scratch

    bkt_params_v4<<<NROWS / 16, 256, 0, stream>>>(X, embed, W0, b0, W1, b1, Wout, bout, paramsb);
    bkt_scan_v4 <<<NROWS / 4,  256, 0, stream>>>(y, paramsb, out_corr, out_lat);
}